// Round 4
// baseline (86.019 us; speedup 1.0000x reference)
//
#include <hip/hip_runtime.h>
#include <hip/hip_bf16.h>

#define TDIM 1024
#define KDIM 32

typedef short bf16x8 __attribute__((ext_vector_type(8)));
typedef float f32x4  __attribute__((ext_vector_type(4)));

__device__ __forceinline__ unsigned short f2bf(float x) {
    __hip_bfloat16 h = __float2bfloat16(x);
    return *reinterpret_cast<unsigned short*>(&h);
}

__device__ __forceinline__ int read_len(const int* __restrict__ lengths32, int b) {
    // int64 little-endian: int32 view at odd index 1 is high word of lengths[0] == 0.
    // int32: lengths[1] in [1,1024], never 0.  (verified rounds 1-3)
    const bool is64 = (lengths32[1] == 0);
    int len = is64 ? lengths32[2 * b] : lengths32[b];
    return len < 1 ? 1 : (len > TDIM ? TDIM : len);
}

// ---------------------------------------------------------------------------
// Chain state: one 32x32 running product P (C-frags) + emission pipeline.
// Loads are 3 steps ahead, exp is 1 step ahead; no cross-lane ops anywhere.
// Group g lanes all load the same float4 pair: ev[4g..4g+3], ev[16+4g..16+4g+3],
// which are exactly the diagonal factors for this lane's C00/C01 (rows 4g+q)
// and C10/C11 (rows 16+4g+q).
// ---------------------------------------------------------------------------
struct Chain {
    f32x4 C00, C01, C10, C11;   // running product fragments (fp32)
    f32x4 e0, e1;               // exp'd emission factors for current step
    f32x4 ra0, ra1;             // raw emissions for step i+1
    f32x4 rb0, rb1;             // raw emissions for step i+2
    int   tcur;                 // absolute t of next load (i+3)
    float sf;                   // pending power-of-2 rescale factor
    int   pend, tote;           // pending exponent, accumulated ledger
};

__device__ __forceinline__ void chain_init(Chain& c, const f32x4* __restrict__ rowbase,
                                           int g, int n, int tstart)
{
#pragma unroll
    for (int q = 0; q < 4; ++q) {
        float d = (4 * g + q == n) ? 1.0f : 0.0f;
        c.C00[q] = d; c.C11[q] = d; c.C01[q] = 0.0f; c.C10[q] = 0.0f;
    }
    f32x4 r0 = rowbase[tstart * 8 + g], r1 = rowbase[tstart * 8 + 4 + g];
#pragma unroll
    for (int e = 0; e < 4; ++e) { c.e0[e] = __expf(r0[e]); c.e1[e] = __expf(r1[e]); }
    int t1 = tstart + 1 > TDIM - 1 ? TDIM - 1 : tstart + 1;
    int t2 = tstart + 2 > TDIM - 1 ? TDIM - 1 : tstart + 2;
    c.ra0 = rowbase[t1 * 8 + g]; c.ra1 = rowbase[t1 * 8 + 4 + g];
    c.rb0 = rowbase[t2 * 8 + g]; c.rb1 = rowbase[t2 * 8 + 4 + g];
    c.tcur = tstart + 3; c.sf = 1.0f; c.pend = 0; c.tote = 0;
}

__device__ __forceinline__ void chain_step(Chain& c, const f32x4* __restrict__ rowbase,
                                           int g, const bf16x8& A0, const bf16x8& A1,
                                           bool fold, bool resc)
{
    // issue loads for step i+3 (clamped, in-bounds; garbage beyond count never consumed)
    int t = c.tcur < (TDIM - 1) ? c.tcur : (TDIM - 1);
    c.tcur++;
    f32x4 l0 = rowbase[t * 8 + g];
    f32x4 l1 = rowbase[t * 8 + 4 + g];
    // exp for step i+1 (independent of the C chain)
    f32x4 en0, en1;
#pragma unroll
    for (int e = 0; e < 4; ++e) { en0[e] = __expf(c.ra0[e]); en1[e] = __expf(c.ra1[e]); }
    if (fold) {
#pragma unroll
        for (int e = 0; e < 4; ++e) { c.e0[e] *= c.sf; c.e1[e] *= c.sf; }
        c.tote += c.pend;
    }
    // B = D * P  (bf16), from this lane's own C values
    f32x4 t0 = c.C00 * c.e0, t1 = c.C10 * c.e1, t2 = c.C01 * c.e0, t3 = c.C11 * c.e1;
    bf16x8 B0, B1;
#pragma unroll
    for (int q = 0; q < 4; ++q) {
        B0[q]     = (short)f2bf(t0[q]);
        B0[q + 4] = (short)f2bf(t1[q]);
        B1[q]     = (short)f2bf(t2[q]);
        B1[q + 4] = (short)f2bf(t3[q]);
    }
    const f32x4 zero = {0.0f, 0.0f, 0.0f, 0.0f};
    c.C00 = __builtin_amdgcn_mfma_f32_16x16x32_bf16(A0, B0, zero, 0, 0, 0);
    c.C01 = __builtin_amdgcn_mfma_f32_16x16x32_bf16(A0, B1, zero, 0, 0, 0);
    c.C10 = __builtin_amdgcn_mfma_f32_16x16x32_bf16(A1, B0, zero, 0, 0, 0);
    c.C11 = __builtin_amdgcn_mfma_f32_16x16x32_bf16(A1, B1, zero, 0, 0, 0);
    if (resc) {
        int bits = __builtin_amdgcn_readfirstlane(__float_as_int(c.C00[0]));
        c.pend = ((bits >> 23) & 255) - 127;
        c.sf = __uint_as_float((unsigned)(127 - c.pend) << 23);
    }
    // shift pipeline
    c.e0 = en0; c.e1 = en1;
    c.ra0 = c.rb0; c.ra1 = c.rb1;
    c.rb0 = l0;    c.rb1 = l1;
}

__device__ __forceinline__ void store_chunk(unsigned int* __restrict__ outP,
                                            const Chain& c, int g, int n)
{
    // bf16 col-major: dword idx = col*16 + row/2
#pragma unroll
    for (int p = 0; p < 2; ++p) {
        int q = 2 * p;
        outP[n * 16        + (4 * g + q) / 2]      = (unsigned)f2bf(c.C00[q]) | ((unsigned)f2bf(c.C00[q + 1]) << 16);
        outP[(16 + n) * 16 + (4 * g + q) / 2]      = (unsigned)f2bf(c.C01[q]) | ((unsigned)f2bf(c.C01[q + 1]) << 16);
        outP[n * 16        + (16 + 4 * g + q) / 2] = (unsigned)f2bf(c.C10[q]) | ((unsigned)f2bf(c.C10[q + 1]) << 16);
        outP[(16 + n) * 16 + (16 + 4 * g + q) / 2] = (unsigned)f2bf(c.C11[q]) | ((unsigned)f2bf(c.C11[q + 1]) << 16);
    }
}

// ---------------- K1: per-(batch, chunk-pair) product matrices ------------
// 4 waves / 256-thread block; wave w handles chunks (2p, 2p+1), p = bx*4+w.
template<int CHS, int NCH>
__global__ __launch_bounds__(256, 4) void crf_chunk_kernel(
    const float* __restrict__ emissions,    // [B, T, K]
    const int*   __restrict__ lengths32,
    const float* __restrict__ transitions,  // [K, K]
    unsigned int* __restrict__ Pout,        // [B][NCH][1024] bf16 as 512 dwords
    int*          __restrict__ toteOut)     // [B][NCH]
{
    const int wid  = threadIdx.x >> 6;
    const int lane = threadIdx.x & 63;
    const int n    = lane & 15;
    const int g    = (lane >> 4) & 3;
    const int p    = blockIdx.x * 4 + wid;
    const int b    = blockIdx.y;
    const int cA   = 2 * p, cB = 2 * p + 1;

    const int len = read_len(lengths32, b);
    const int tsA = 1 + cA * CHS, tsB = 1 + cB * CHS;
    int cntA = len - tsA; cntA = cntA > CHS ? CHS : cntA;
    int cntB = len - tsB; cntB = cntB > CHS ? CHS : cntB;
    if (cntA <= 0) return;                 // adjacent pairing: cntB <= cntA
    if (cntB < 0) cntB = 0;

    // slot -> contraction-row map rho(g,e); static A-frags = exp(trans)^T
    bf16x8 A0, A1;
#pragma unroll
    for (int e = 0; e < 8; ++e) {
        int rho = (e < 4) ? (4 * g + e) : (16 + 4 * g + (e - 4));
        A0[e] = (short)f2bf(__expf(transitions[rho * KDIM + n]));
        A1[e] = (short)f2bf(__expf(transitions[rho * KDIM + 16 + n]));
    }

    const f32x4* rowbase = (const f32x4*)(emissions + (size_t)b * TDIM * KDIM);

    Chain A, B;
    chain_init(A, rowbase, g, n, tsA);
    if (cntB > 0) chain_init(B, rowbase, g, n, tsB);

    const int fgA = cntA >> 2, remA = cntA & 3;
    const int fgB = cntB >> 2, remB = cntB > 0 ? (cntB & 3) : 0;
    const int m   = fgB;   // == min(fgA,fgB) since cntB <= cntA

    for (int k = 0; k < m; ++k) {
        chain_step(A, rowbase, g, A0, A1, true,  false);
        chain_step(B, rowbase, g, A0, A1, true,  false);
        chain_step(A, rowbase, g, A0, A1, false, false);
        chain_step(B, rowbase, g, A0, A1, false, false);
        chain_step(A, rowbase, g, A0, A1, false, false);
        chain_step(B, rowbase, g, A0, A1, false, false);
        chain_step(A, rowbase, g, A0, A1, false, true);
        chain_step(B, rowbase, g, A0, A1, false, true);
    }
    for (int k = m; k < fgA; ++k) {
        chain_step(A, rowbase, g, A0, A1, true,  false);
        chain_step(A, rowbase, g, A0, A1, false, false);
        chain_step(A, rowbase, g, A0, A1, false, false);
        chain_step(A, rowbase, g, A0, A1, false, true);
    }
    for (int u = 0; u < remA; ++u) chain_step(A, rowbase, g, A0, A1, true, true);
    for (int u = 0; u < remB; ++u) chain_step(B, rowbase, g, A0, A1, true, true);

    store_chunk(Pout + ((size_t)b * NCH + cA) * 512, A, g, n);
    if (lane == 0) toteOut[b * NCH + cA] = A.tote;
    if (cntB > 0) {
        store_chunk(Pout + ((size_t)b * NCH + cB) * 512, B, g, n);
        if (lane == 0) toteOut[b * NCH + cB] = B.tote;
    }
}

// ---------------- K2: chain chunk matrices through alpha ------------------
// P is col-major: lane j's column = 64 contiguous bytes -> register prefetch,
// no LDS, chunk c+1 loads overlap chunk c's FMA chain.
template<int NCH, int CHS>
__global__ __launch_bounds__(64) void crf_combine_kernel(
    const float* __restrict__ emissions,
    const int*   __restrict__ lengths32,
    const float* __restrict__ head_t,
    const float* __restrict__ last_t,
    const unsigned short* __restrict__ Pbuf,  // [B][NCH][1024] bf16 col-major
    const int*   __restrict__ toteBuf,
    float*       __restrict__ out)
{
    const int b    = blockIdx.x;
    const int lane = threadIdx.x;
    const int j    = lane & 31;

    const int len = read_len(lengths32, b);
    int nAlive = (len - 1 + CHS - 1) / CHS;
    if (nAlive > NCH) nAlive = NCH;

    float alpha = __expf(head_t[j] + emissions[(size_t)b * TDIM * KDIM + j]);
    int tote = 0;

    const char* base = (const char*)(Pbuf + (size_t)b * NCH * 1024);
    uint4 P0[4], Pn[4];
    {
        const uint4* pc = (const uint4*)(base + (size_t)j * 64);
#pragma unroll
        for (int w = 0; w < 4; ++w) P0[w] = pc[w];
    }

    for (int cix = 0; cix < nAlive; ++cix) {
        int cn = (cix + 1 < NCH) ? cix + 1 : cix;
        const uint4* pc = (const uint4*)(base + (size_t)cn * 2048 + (size_t)j * 64);
#pragma unroll
        for (int w = 0; w < 4; ++w) Pn[w] = pc[w];

        float a0 = 0.0f, a1 = 0.0f;
#pragma unroll
        for (int w = 0; w < 4; ++w) {
            unsigned d[4] = {P0[w].x, P0[w].y, P0[w].z, P0[w].w};
#pragma unroll
            for (int h = 0; h < 4; ++h) {
                int r = w * 8 + h * 2;
                float plo = __uint_as_float(d[h] << 16);           // row r,   col j
                float phi = __uint_as_float(d[h] & 0xffff0000u);   // row r+1, col j
                float al  = __int_as_float(__builtin_amdgcn_readlane(__float_as_int(alpha), r));
                float ah  = __int_as_float(__builtin_amdgcn_readlane(__float_as_int(alpha), r + 1));
                a0 = fmaf(plo, al, a0);
                a1 = fmaf(phi, ah, a1);
            }
        }
        float acc = a0 + a1;
        int bits = __builtin_amdgcn_readfirstlane(__float_as_int(acc));
        int s = ((bits >> 23) & 255) - 127;
        alpha = acc * __uint_as_float((unsigned)(127 - s) << 23);
        tote += s + toteBuf[b * NCH + cix];
#pragma unroll
        for (int w = 0; w < 4; ++w) P0[w] = Pn[w];
    }

    float pp = alpha * __expf(last_t[j]);
#pragma unroll
    for (int mm = 16; mm >= 1; mm >>= 1)
        pp += __shfl_xor(pp, mm, 64);

    if (lane == 0)
        out[b] = __logf(pp) + (float)tote * 0.69314718055994531f;
}

extern "C" void kernel_launch(void* const* d_in, const int* in_sizes, int n_in,
                              void* d_out, int out_size, void* d_ws, size_t ws_size,
                              hipStream_t stream)
{
    const float* emissions   = (const float*)d_in[0];
    const int*   lengths     = (const int*)d_in[1];
    const float* transitions = (const float*)d_in[2];
    const float* head_t      = (const float*)d_in[3];
    const float* last_t      = (const float*)d_in[4];
    float* out = (float*)d_out;
    const int B = out_size;  // 512

    unsigned int* Pbuf = (unsigned int*)d_ws;

    const size_t need16 = (size_t)B * 16 * 2048 + (size_t)B * 16 * 4;
    if (ws_size >= need16) {
        int* toteBf = (int*)((char*)d_ws + (size_t)B * 16 * 2048);
        dim3 g1(2, B);   // 2 blocks x 4 waves = 8 pairs = 16 chunks
        crf_chunk_kernel<64, 16><<<g1, 256, 0, stream>>>(emissions, lengths, transitions, Pbuf, toteBf);
        crf_combine_kernel<16, 64><<<B, 64, 0, stream>>>(emissions, lengths, head_t, last_t,
                                                         (const unsigned short*)Pbuf, toteBf, out);
    } else {
        int* toteBf = (int*)((char*)d_ws + (size_t)B * 8 * 2048);
        dim3 g1(1, B);   // 1 block x 4 waves = 4 pairs = 8 chunks
        crf_chunk_kernel<128, 8><<<g1, 256, 0, stream>>>(emissions, lengths, transitions, Pbuf, toteBf);
        crf_combine_kernel<8, 128><<<B, 64, 0, stream>>>(emissions, lengths, head_t, last_t,
                                                         (const unsigned short*)Pbuf, toteBf, out);
    }
}

// Round 5
// 76.908 us; speedup vs baseline: 1.1185x; 1.1185x over previous
//
#include <hip/hip_runtime.h>
#include <hip/hip_bf16.h>

#define TDIM 1024
#define KDIM 32

typedef short bf16x8 __attribute__((ext_vector_type(8)));
typedef float f32x4  __attribute__((ext_vector_type(4)));

__device__ __forceinline__ unsigned short f2bf(float x) {
    __hip_bfloat16 h = __float2bfloat16(x);
    return *reinterpret_cast<unsigned short*>(&h);
}

__device__ __forceinline__ int read_len(const int* __restrict__ lengths32, int b) {
    // int64 little-endian: int32 view at odd index 1 is high word of lengths[0] == 0.
    // int32: lengths[1] in [1,1024], never 0.  (verified rounds 1-4)
    const bool is64 = (lengths32[1] == 0);
    int len = is64 ? lengths32[2 * b] : lengths32[b];
    return len < 1 ? 1 : (len > TDIM ? TDIM : len);
}

// ---------------- K1: per-(batch, chunk) 32x32 product matrix -------------
// P_chunk = prod_{t in [t0, min(t0+CHS, len)) } E^T D_t,  t0 = 1 + c*CHS.
// Emissions for the whole chunk staged to LDS via async global_load_lds,
// exp'd in place once; hot loop reads ready factors with ds_read_b128.
// bf16 col-major output (addr = col*32+row), power-of-2 scale ledger.
template<int CHS, int NCH>
__global__ __launch_bounds__(256, 6) void crf_chunk_kernel(
    const float* __restrict__ emissions,    // [B, T, K]
    const int*   __restrict__ lengths32,
    const float* __restrict__ transitions,  // [K, K]
    unsigned int* __restrict__ Pout,        // [B][NCH][1024] bf16 as 512 dwords
    int*          __restrict__ toteOut)     // [B][NCH]
{
    __shared__ float lds_all[4][CHS * KDIM];   // 4KB per wave at CHS=32
    const int wid  = threadIdx.x >> 6;
    const int lane = threadIdx.x & 63;
    const int n    = lane & 15;
    const int g    = (lane >> 4) & 3;
    const int c    = blockIdx.x * 4 + wid;
    const int b    = blockIdx.y;

    const int len = read_len(lengths32, b);
    const int t0  = 1 + c * CHS;
    int count = len - t0; count = count > CHS ? CHS : count;
    if (count <= 0) return;                  // dead chunk: exit immediately

    // ---- stage CHS emission rows into this wave's LDS slice (async DMA) ----
    // If the chunk window would run past T, shift it down (shift in {0,1};
    // only possible for the last chunk, which always has count < CHS).
    int base_t = t0, shift = 0;
    if (t0 + CHS > TDIM) { base_t = TDIM - CHS; shift = t0 - base_t; }
    const float* src = emissions + ((size_t)b * TDIM + base_t) * KDIM;
    float* myl = lds_all[wid];
    constexpr int NSEG = CHS * KDIM / 256;   // 1KB segments (64 lanes x 16B)
#pragma unroll
    for (int s = 0; s < NSEG; ++s)
        __builtin_amdgcn_global_load_lds(
            (const __attribute__((address_space(1))) void*)(src + s * 256 + lane * 4),
            (__attribute__((address_space(3))) void*)(myl + s * 256), 16, 0, 0);

    // A-frags while the DMA is in flight: A = (E^T) in MFMA A layout
    bf16x8 A0, A1;
#pragma unroll
    for (int e = 0; e < 8; ++e) {
        int rho = (e < 4) ? (4 * g + e) : (16 + 4 * g + (e - 4));
        A0[e] = (short)f2bf(__expf(transitions[rho * KDIM + n]));
        A1[e] = (short)f2bf(__expf(transitions[rho * KDIM + 16 + n]));
    }

    asm volatile("s_waitcnt vmcnt(0)" ::: "memory");
    __builtin_amdgcn_sched_barrier(0);

    // ---- exp pre-pass in place (per-wave slice, no barriers needed) ----
    f32x4* mylv = (f32x4*)myl;
#pragma unroll
    for (int r = 0; r < NSEG; ++r) {
        f32x4 v = mylv[r * 64 + lane];
#pragma unroll
        for (int e = 0; e < 4; ++e) v[e] = __expf(v[e]);
        mylv[r * 64 + lane] = v;
    }
    asm volatile("s_waitcnt lgkmcnt(0)" ::: "memory");
    __builtin_amdgcn_sched_barrier(0);

    // ---- running product in C-frags ----
    f32x4 C00, C01, C10, C11;
#pragma unroll
    for (int q = 0; q < 4; ++q) {
        float d = (4 * g + q == n) ? 1.0f : 0.0f;
        C00[q] = d; C11[q] = d; C01[q] = 0.0f; C10[q] = 0.0f;
    }
    float sf = 1.0f; int pend = 0, tote = 0;
    const f32x4 zero = {0.0f, 0.0f, 0.0f, 0.0f};

    auto DOSTEP = [&](f32x4 e0, f32x4 e1) {
        f32x4 t0v = C00 * e0, t1v = C10 * e1, t2v = C01 * e0, t3v = C11 * e1;
        bf16x8 B0, B1;
#pragma unroll
        for (int q = 0; q < 4; ++q) {
            B0[q]     = (short)f2bf(t0v[q]);
            B0[q + 4] = (short)f2bf(t1v[q]);
            B1[q]     = (short)f2bf(t2v[q]);
            B1[q + 4] = (short)f2bf(t3v[q]);
        }
        C00 = __builtin_amdgcn_mfma_f32_16x16x32_bf16(A0, B0, zero, 0, 0, 0);
        C01 = __builtin_amdgcn_mfma_f32_16x16x32_bf16(A0, B1, zero, 0, 0, 0);
        C10 = __builtin_amdgcn_mfma_f32_16x16x32_bf16(A1, B0, zero, 0, 0, 0);
        C11 = __builtin_amdgcn_mfma_f32_16x16x32_bf16(A1, B1, zero, 0, 0, 0);
    };
    auto RESCALE = [&]() {
        int bits = __builtin_amdgcn_readfirstlane(__float_as_int(C00[0]));
        pend = ((bits >> 23) & 255) - 127;
        sf = __uint_as_float((unsigned)(127 - pend) << 23);
    };

    if (count == CHS) {          // full chunk (shift == 0 by construction)
#pragma unroll 8
        for (int tau = 0; tau < CHS; ++tau) {
            f32x4 e0 = mylv[tau * 8 + g];
            f32x4 e1 = mylv[tau * 8 + 4 + g];
            if ((tau & 3) == 0) {
#pragma unroll
                for (int e = 0; e < 4; ++e) { e0[e] *= sf; e1[e] *= sf; }
                tote += pend;
            }
            DOSTEP(e0, e1);
            if ((tau & 3) == 3) RESCALE();
        }
    } else {                     // boundary chunk: per-step fold/rescale
        for (int tau = 0; tau < count; ++tau) {
            f32x4 e0 = mylv[(tau + shift) * 8 + g];
            f32x4 e1 = mylv[(tau + shift) * 8 + 4 + g];
#pragma unroll
            for (int e = 0; e < 4; ++e) { e0[e] *= sf; e1[e] *= sf; }
            tote += pend;
            DOSTEP(e0, e1);
            RESCALE();
        }
    }

    // store bf16 col-major: dword idx = col*16 + row/2
    unsigned int* outP = Pout + ((size_t)b * NCH + c) * 512;
#pragma unroll
    for (int p = 0; p < 2; ++p) {
        int q = 2 * p;
        outP[n * 16        + (4 * g + q) / 2]      = (unsigned)f2bf(C00[q]) | ((unsigned)f2bf(C00[q + 1]) << 16);
        outP[(16 + n) * 16 + (4 * g + q) / 2]      = (unsigned)f2bf(C01[q]) | ((unsigned)f2bf(C01[q + 1]) << 16);
        outP[n * 16        + (16 + 4 * g + q) / 2] = (unsigned)f2bf(C10[q]) | ((unsigned)f2bf(C10[q + 1]) << 16);
        outP[(16 + n) * 16 + (16 + 4 * g + q) / 2] = (unsigned)f2bf(C11[q]) | ((unsigned)f2bf(C11[q + 1]) << 16);
    }
    if (lane == 0) toteOut[b * NCH + c] = tote;
}

// ---------------- K2: chain chunk matrices through alpha ------------------
// Lane j's column of P = 64 contiguous bytes; depth-2 register prefetch.
template<int NCH, int CHS>
__global__ __launch_bounds__(64) void crf_combine_kernel(
    const float* __restrict__ emissions,
    const int*   __restrict__ lengths32,
    const float* __restrict__ head_t,
    const float* __restrict__ last_t,
    const unsigned short* __restrict__ Pbuf,  // [B][NCH][1024] bf16 col-major
    const int*   __restrict__ toteBuf,
    float*       __restrict__ out)
{
    const int b    = blockIdx.x;
    const int lane = threadIdx.x;
    const int j    = lane & 31;

    const int len = read_len(lengths32, b);
    int nAlive = (len - 1 + CHS - 1) / CHS;
    if (nAlive > NCH) nAlive = NCH;

    float alpha = __expf(head_t[j] + emissions[(size_t)b * TDIM * KDIM + j]);
    int tote = 0;

    const char* base = (const char*)(Pbuf + (size_t)b * NCH * 1024);

    auto LOADC = [&](int cix, uint4 dst[4]) {
        int cc = cix < NCH ? cix : NCH - 1;
        const uint4* pc = (const uint4*)(base + (size_t)cc * 2048 + (size_t)j * 64);
#pragma unroll
        for (int w = 0; w < 4; ++w) dst[w] = pc[w];
    };

    uint4 cur[4], nx1[4];
    LOADC(0, cur);
    LOADC(1, nx1);

    for (int cix = 0; cix < nAlive; ++cix) {
        uint4 nx2[4];
        LOADC(cix + 2, nx2);

        float a0 = 0.0f, a1 = 0.0f;
#pragma unroll
        for (int w = 0; w < 4; ++w) {
            unsigned d[4] = {cur[w].x, cur[w].y, cur[w].z, cur[w].w};
#pragma unroll
            for (int h = 0; h < 4; ++h) {
                int r = w * 8 + h * 2;
                float plo = __uint_as_float(d[h] << 16);           // row r,   col j
                float phi = __uint_as_float(d[h] & 0xffff0000u);   // row r+1, col j
                float al  = __int_as_float(__builtin_amdgcn_readlane(__float_as_int(alpha), r));
                float ah  = __int_as_float(__builtin_amdgcn_readlane(__float_as_int(alpha), r + 1));
                a0 = fmaf(plo, al, a0);
                a1 = fmaf(phi, ah, a1);
            }
        }
        float acc = a0 + a1;
        int bits = __builtin_amdgcn_readfirstlane(__float_as_int(acc));
        int s = ((bits >> 23) & 255) - 127;
        alpha = acc * __uint_as_float((unsigned)(127 - s) << 23);
        tote += s + toteBuf[b * NCH + cix];
#pragma unroll
        for (int w = 0; w < 4; ++w) { cur[w] = nx1[w]; nx1[w] = nx2[w]; }
    }

    float pp = alpha * __expf(last_t[j]);
#pragma unroll
    for (int mm = 16; mm >= 1; mm >>= 1)
        pp += __shfl_xor(pp, mm, 64);

    if (lane == 0)
        out[b] = __logf(pp) + (float)tote * 0.69314718055994531f;
}

extern "C" void kernel_launch(void* const* d_in, const int* in_sizes, int n_in,
                              void* d_out, int out_size, void* d_ws, size_t ws_size,
                              hipStream_t stream)
{
    const float* emissions   = (const float*)d_in[0];
    const int*   lengths     = (const int*)d_in[1];
    const float* transitions = (const float*)d_in[2];
    const float* head_t      = (const float*)d_in[3];
    const float* last_t      = (const float*)d_in[4];
    float* out = (float*)d_out;
    const int B = out_size;  // 512

    unsigned int* Pbuf = (unsigned int*)d_ws;

    const size_t need32 = (size_t)B * 32 * 2048 + (size_t)B * 32 * 4;
    if (ws_size >= need32) {
        int* toteBf = (int*)((char*)d_ws + (size_t)B * 32 * 2048);
        dim3 g1(8, B);    // 8 blocks x 4 waves = 32 chunks of 32 steps
        crf_chunk_kernel<32, 32><<<g1, 256, 0, stream>>>(emissions, lengths, transitions, Pbuf, toteBf);
        crf_combine_kernel<32, 32><<<B, 64, 0, stream>>>(emissions, lengths, head_t, last_t,
                                                         (const unsigned short*)Pbuf, toteBf, out);
    } else {
        int* toteBf = (int*)((char*)d_ws + (size_t)B * 16 * 2048);
        dim3 g1(4, B);    // 4 blocks x 4 waves = 16 chunks of 64 steps
        crf_chunk_kernel<64, 16><<<g1, 256, 0, stream>>>(emissions, lengths, transitions, Pbuf, toteBf);
        crf_combine_kernel<16, 64><<<B, 64, 0, stream>>>(emissions, lengths, head_t, last_t,
                                                         (const unsigned short*)Pbuf, toteBf, out);
    }
}

// Round 6
// 65.108 us; speedup vs baseline: 1.3212x; 1.1812x over previous
//
#include <hip/hip_runtime.h>
#include <hip/hip_bf16.h>

#define TDIM 1024
#define KDIM 32

typedef short bf16x8 __attribute__((ext_vector_type(8)));
typedef float f32x4  __attribute__((ext_vector_type(4)));

__device__ __forceinline__ unsigned short f2bf(float x) {
    __hip_bfloat16 h = __float2bfloat16(x);
    return *reinterpret_cast<unsigned short*>(&h);
}

__device__ __forceinline__ int read_len(const int* __restrict__ lengths32, int b) {
    // int64 little-endian: int32 view at odd index 1 is high word of lengths[0] == 0.
    // int32: lengths[1] in [1,1024], never 0.  (verified rounds 1-5)
    const bool is64 = (lengths32[1] == 0);
    int len = is64 ? lengths32[2 * b] : lengths32[b];
    return len < 1 ? 1 : (len > TDIM ? TDIM : len);
}

// ---------------- K1: per-(batch, chunk) 32x32 product matrix -------------
// P_chunk = prod_t (E^T D_t).  Key change vs round 5: fold D_t into the A
// operand (A_t[.,k] = E^T[.,k] * d[k]); B operand = bf16(previous C) directly.
// Critical path per step: MFMA -> cvt -> MFMA. A-build is emission-only.
template<int CHS, int NCH>
__global__ __launch_bounds__(256, 4) void crf_chunk_kernel(
    const float* __restrict__ emissions,    // [B, T, K]
    const int*   __restrict__ lengths32,
    const float* __restrict__ transitions,  // [K, K]
    unsigned int* __restrict__ Pout,        // [B][NCH][1024] bf16 as 512 dwords
    int*          __restrict__ toteOut)     // [B][NCH]
{
    __shared__ float lds_all[4][CHS * KDIM];
    const int wid  = threadIdx.x >> 6;
    const int lane = threadIdx.x & 63;
    const int n    = lane & 15;
    const int g    = (lane >> 4) & 3;
    const int c    = blockIdx.x * 4 + wid;
    const int b    = blockIdx.y;

    const int len = read_len(lengths32, b);
    const int t0  = 1 + c * CHS;
    int count = len - t0; count = count > CHS ? CHS : count;
    if (count <= 0) return;                  // dead chunk

    // ---- stage CHS emission rows into this wave's LDS slice (async DMA) ----
    int base_t = t0, shift = 0;
    if (t0 + CHS > TDIM) { base_t = TDIM - CHS; shift = t0 - base_t; }
    const float* src = emissions + ((size_t)b * TDIM + base_t) * KDIM;
    float* myl = lds_all[wid];
    constexpr int NSEG = CHS * KDIM / 256;   // 1KB segments
#pragma unroll
    for (int s = 0; s < NSEG; ++s)
        __builtin_amdgcn_global_load_lds(
            (const __attribute__((address_space(1))) void*)(src + s * 256 + lane * 4),
            (__attribute__((address_space(3))) void*)(myl + s * 256), 16, 0, 0);

    // static E^T factors in f32 (A-operand element e <-> contraction k = rho(g,e))
    f32x4 Ef00, Ef01, Ef10, Ef11;
#pragma unroll
    for (int e = 0; e < 4; ++e) {
        Ef00[e] = __expf(transitions[(4 * g + e) * KDIM + n]);
        Ef01[e] = __expf(transitions[(16 + 4 * g + e) * KDIM + n]);
        Ef10[e] = __expf(transitions[(4 * g + e) * KDIM + 16 + n]);
        Ef11[e] = __expf(transitions[(16 + 4 * g + e) * KDIM + 16 + n]);
    }

    asm volatile("s_waitcnt vmcnt(0)" ::: "memory");
    __builtin_amdgcn_sched_barrier(0);

    // ---- exp pre-pass in place (per-wave slice) ----
    f32x4* mylv = (f32x4*)myl;
#pragma unroll
    for (int r = 0; r < NSEG; ++r) {
        f32x4 v = mylv[r * 64 + lane];
#pragma unroll
        for (int e = 0; e < 4; ++e) v[e] = __expf(v[e]);
        mylv[r * 64 + lane] = v;
    }
    asm volatile("s_waitcnt lgkmcnt(0)" ::: "memory");
    __builtin_amdgcn_sched_barrier(0);

    // ---- running product in C-frags ----
    f32x4 C00, C01, C10, C11;
#pragma unroll
    for (int q = 0; q < 4; ++q) {
        float d = (4 * g + q == n) ? 1.0f : 0.0f;
        C00[q] = d; C11[q] = d; C01[q] = 0.0f; C10[q] = 0.0f;
    }
    float sf = 1.0f; int pend = 0, tote = 0;
    const f32x4 zero = {0.0f, 0.0f, 0.0f, 0.0f};

    auto STEP = [&](f32x4 e0, f32x4 e1) {
        // A_t = E^T scaled per-column by d (emission-only -> off critical path)
        f32x4 a00 = Ef00 * e0, a01 = Ef01 * e1, a10 = Ef10 * e0, a11 = Ef11 * e1;
        bf16x8 A0, A1, B0, B1;
#pragma unroll
        for (int q = 0; q < 4; ++q) {
            A0[q]     = (short)f2bf(a00[q]);
            A0[q + 4] = (short)f2bf(a01[q]);
            A1[q]     = (short)f2bf(a10[q]);
            A1[q + 4] = (short)f2bf(a11[q]);
            B0[q]     = (short)f2bf(C00[q]);   // B = bf16(previous C): the only
            B0[q + 4] = (short)f2bf(C10[q]);   // ops on the MFMA->MFMA chain
            B1[q]     = (short)f2bf(C01[q]);
            B1[q + 4] = (short)f2bf(C11[q]);
        }
        C00 = __builtin_amdgcn_mfma_f32_16x16x32_bf16(A0, B0, zero, 0, 0, 0);
        C01 = __builtin_amdgcn_mfma_f32_16x16x32_bf16(A0, B1, zero, 0, 0, 0);
        C10 = __builtin_amdgcn_mfma_f32_16x16x32_bf16(A1, B0, zero, 0, 0, 0);
        C11 = __builtin_amdgcn_mfma_f32_16x16x32_bf16(A1, B1, zero, 0, 0, 0);
    };
    auto RESCALE = [&]() {
        int bits = __builtin_amdgcn_readfirstlane(__float_as_int(C00[0]));
        pend = ((bits >> 23) & 255) - 127;
        sf = __uint_as_float((unsigned)(127 - pend) << 23);
    };

    if (count == CHS) {
        // depth-2 LDS read pipeline, static slot = u&1
        f32x4 pipe[2][2];
        pipe[0][0] = mylv[0 * 8 + g]; pipe[0][1] = mylv[0 * 8 + 4 + g];
        pipe[1][0] = mylv[1 * 8 + g]; pipe[1][1] = mylv[1 * 8 + 4 + g];
        constexpr int NQ = CHS / 4;
        for (int tq = 0; tq < NQ; ++tq) {
#pragma unroll
            for (int u = 0; u < 4; ++u) {
                const int s = u & 1;
                f32x4 e0 = pipe[s][0], e1 = pipe[s][1];
                int tl = 4 * tq + u + 2; if (tl > CHS - 1) tl = CHS - 1;
                pipe[s][0] = mylv[tl * 8 + g];
                pipe[s][1] = mylv[tl * 8 + 4 + g];
                if (u == 0) {
#pragma unroll
                    for (int e = 0; e < 4; ++e) { e0[e] *= sf; e1[e] *= sf; }
                    tote += pend;
                }
                STEP(e0, e1);
                if (u == 3) RESCALE();
            }
        }
    } else {
        // boundary chunk: per-step fold + rescale
        for (int tau = 0; tau < count; ++tau) {
            f32x4 e0 = mylv[(tau + shift) * 8 + g];
            f32x4 e1 = mylv[(tau + shift) * 8 + 4 + g];
#pragma unroll
            for (int e = 0; e < 4; ++e) { e0[e] *= sf; e1[e] *= sf; }
            tote += pend;
            STEP(e0, e1);
            RESCALE();
        }
    }

    // store bf16 col-major: dword idx = col*16 + row/2
    unsigned int* outP = Pout + ((size_t)b * NCH + c) * 512;
#pragma unroll
    for (int p = 0; p < 2; ++p) {
        int q = 2 * p;
        outP[n * 16        + (4 * g + q) / 2]      = (unsigned)f2bf(C00[q]) | ((unsigned)f2bf(C00[q + 1]) << 16);
        outP[(16 + n) * 16 + (4 * g + q) / 2]      = (unsigned)f2bf(C01[q]) | ((unsigned)f2bf(C01[q + 1]) << 16);
        outP[n * 16        + (16 + 4 * g + q) / 2] = (unsigned)f2bf(C10[q]) | ((unsigned)f2bf(C10[q + 1]) << 16);
        outP[(16 + n) * 16 + (16 + 4 * g + q) / 2] = (unsigned)f2bf(C11[q]) | ((unsigned)f2bf(C11[q + 1]) << 16);
    }
    if (lane == 0) toteOut[b * NCH + c] = tote;
}

// ---------------- K2: chain chunk matrices through alpha ------------------
template<int NCH, int CHS>
__global__ __launch_bounds__(64) void crf_combine_kernel(
    const float* __restrict__ emissions,
    const int*   __restrict__ lengths32,
    const float* __restrict__ head_t,
    const float* __restrict__ last_t,
    const unsigned short* __restrict__ Pbuf,  // [B][NCH][1024] bf16 col-major
    const int*   __restrict__ toteBuf,
    float*       __restrict__ out)
{
    const int b    = blockIdx.x;
    const int lane = threadIdx.x;
    const int j    = lane & 31;

    const int len = read_len(lengths32, b);
    int nAlive = (len - 1 + CHS - 1) / CHS;
    if (nAlive > NCH) nAlive = NCH;

    float alpha = __expf(head_t[j] + emissions[(size_t)b * TDIM * KDIM + j]);
    int tote = 0;

    const char* base = (const char*)(Pbuf + (size_t)b * NCH * 1024);

    auto LOADC = [&](int cix, uint4 dst[4]) {
        int cc = cix < NCH ? cix : NCH - 1;
        const uint4* pc = (const uint4*)(base + (size_t)cc * 2048 + (size_t)j * 64);
#pragma unroll
        for (int w = 0; w < 4; ++w) dst[w] = pc[w];
    };

    uint4 cur[4], nx1[4];
    LOADC(0, cur);
    LOADC(1, nx1);

    for (int cix = 0; cix < nAlive; ++cix) {
        uint4 nx2[4];
        LOADC(cix + 2, nx2);

        float a0 = 0.0f, a1 = 0.0f;
#pragma unroll
        for (int w = 0; w < 4; ++w) {
            unsigned d[4] = {cur[w].x, cur[w].y, cur[w].z, cur[w].w};
#pragma unroll
            for (int h = 0; h < 4; ++h) {
                int r = w * 8 + h * 2;
                float plo = __uint_as_float(d[h] << 16);           // row r,   col j
                float phi = __uint_as_float(d[h] & 0xffff0000u);   // row r+1, col j
                float al  = __int_as_float(__builtin_amdgcn_readlane(__float_as_int(alpha), r));
                float ah  = __int_as_float(__builtin_amdgcn_readlane(__float_as_int(alpha), r + 1));
                a0 = fmaf(plo, al, a0);
                a1 = fmaf(phi, ah, a1);
            }
        }
        float acc = a0 + a1;
        int bits = __builtin_amdgcn_readfirstlane(__float_as_int(acc));
        int s = ((bits >> 23) & 255) - 127;
        alpha = acc * __uint_as_float((unsigned)(127 - s) << 23);
        tote += s + toteBuf[b * NCH + cix];
#pragma unroll
        for (int w = 0; w < 4; ++w) { cur[w] = nx1[w]; nx1[w] = nx2[w]; }
    }

    float pp = alpha * __expf(last_t[j]);
#pragma unroll
    for (int mm = 16; mm >= 1; mm >>= 1)
        pp += __shfl_xor(pp, mm, 64);

    if (lane == 0)
        out[b] = __logf(pp) + (float)tote * 0.69314718055994531f;
}

extern "C" void kernel_launch(void* const* d_in, const int* in_sizes, int n_in,
                              void* d_out, int out_size, void* d_ws, size_t ws_size,
                              hipStream_t stream)
{
    const float* emissions   = (const float*)d_in[0];
    const int*   lengths     = (const int*)d_in[1];
    const float* transitions = (const float*)d_in[2];
    const float* head_t      = (const float*)d_in[3];
    const float* last_t      = (const float*)d_in[4];
    float* out = (float*)d_out;
    const int B = out_size;  // 512

    unsigned int* Pbuf = (unsigned int*)d_ws;

    const size_t need16 = (size_t)B * 16 * 2048 + (size_t)B * 16 * 4;
    if (ws_size >= need16) {
        int* toteBf = (int*)((char*)d_ws + (size_t)B * 16 * 2048);
        dim3 g1(4, B);    // 4 blocks x 4 waves = 16 chunks of 64 steps
        crf_chunk_kernel<64, 16><<<g1, 256, 0, stream>>>(emissions, lengths, transitions, Pbuf, toteBf);
        crf_combine_kernel<16, 64><<<B, 64, 0, stream>>>(emissions, lengths, head_t, last_t,
                                                         (const unsigned short*)Pbuf, toteBf, out);
    } else {
        int* toteBf = (int*)((char*)d_ws + (size_t)B * 8 * 2048);
        dim3 g1(2, B);    // 2 blocks x 4 waves = 8 chunks of 128 steps
        crf_chunk_kernel<128, 8><<<g1, 256, 0, stream>>>(emissions, lengths, transitions, Pbuf, toteBf);
        crf_combine_kernel<8, 128><<<B, 64, 0, stream>>>(emissions, lengths, head_t, last_t,
                                                         (const unsigned short*)Pbuf, toteBf, out);
    }
}